// Round 3
// baseline (227.539 us; speedup 1.0000x reference)
//
#include <hip/hip_runtime.h>
#include <math.h>

#define DT_F      0.1f
#define PI_F      3.14159265358979323846f
#define TWO_PI_F  6.28318530717958647692f
// exp(-8.0) precomputed
#define EXP_M8_F  0.00033546262790251185f

// 4 elements per thread: every per-array slice is a whole number of float4s.
//   x/th: 3 float4 per thread, P: 9, a: 2  -> 17 independent loads, no barriers.
__global__ __launch_bounds__(256) void belief_step_kernel(
    const float* __restrict__ x,
    const float* __restrict__ P,
    const float* __restrict__ a,
    const float* __restrict__ th,
    float* __restrict__ out_x,
    float* __restrict__ out_P)
{
    const long long t = (long long)blockIdx.x * 256 + threadIdx.x; // thread id
    // float4 bases for this thread's 4 elements
    const float4* x4 = (const float4*)x  + t * 3;
    const float4* P4 = (const float4*)P  + t * 9;
    const float4* a4 = (const float4*)a  + t * 2;
    const float4* t4 = (const float4*)th + t * 3;

    // ---- issue all 17 loads up front (max MLP, no barriers) ----
    float4 xv4[3], pv4[9], av4[2], tv4[3];
    #pragma unroll
    for (int i = 0; i < 9; ++i) pv4[i] = P4[i];
    #pragma unroll
    for (int i = 0; i < 3; ++i) xv4[i] = x4[i];
    #pragma unroll
    for (int i = 0; i < 3; ++i) tv4[i] = t4[i];
    #pragma unroll
    for (int i = 0; i < 2; ++i) av4[i] = a4[i];

    const float* xv = (const float*)xv4;   // 12 floats: [px,py,ang] x4
    const float* pv = (const float*)pv4;   // 36 floats: 9 per element
    const float* av = (const float*)av4;   // 8 floats:  [a0,a1] x4
    const float* tv = (const float*)tv4;   // 12 floats: [t0,t1,t2] x4

    float4 ox4[3], oP4_[9];
    float* ox = (float*)ox4;               // 12 floats out (x_)
    float* oP = (float*)oP4_;              // 36 floats out (P_)

    #pragma unroll
    for (int j = 0; j < 4; ++j) {
        const float px  = xv[3*j + 0];
        const float py  = xv[3*j + 1];
        const float ang = xv[3*j + 2];
        const float a0  = av[2*j + 0];
        const float a1  = av[2*j + 1];
        const float t0  = tv[3*j + 0];
        const float t1  = tv[3*j + 1];
        const float t2  = tv[3*j + 2];
        const float* Pm = pv + 9*j;

        // range_angle(ang - theta1*a1*DT)
        const float ar   = ang - t1 * a1 * DT_F;
        const float ang_ = ar - TWO_PI_F * floorf((ar + PI_F) / TWO_PI_F);
        float s, c;
        sincosf(ang_, &s, &c);
        const float v = t0 * a0 * DT_F;

        float px_ = fminf(fmaxf(px + v * c, -1.0f), 1.0f);
        float py_ = fminf(fmaxf(py + v * s, -1.0f), 1.0f);

        // A = I + w0 at (0,2), w1 at (1,2);  w0 = -v*s, w1 = v*c
        const float w0 = -v * s;
        const float w1 =  v * c;

        // AP = A @ P
        float AP0[3], AP1[3];
        #pragma unroll
        for (int k = 0; k < 3; ++k) {
            AP0[k] = fmaf(w0, Pm[6 + k], Pm[0 + k]);
            AP1[k] = fmaf(w1, Pm[6 + k], Pm[3 + k]);
        }

        // M = AP @ A^T
        const float M00 = fmaf(w0, AP0[2], AP0[0]);
        const float M01 = fmaf(w1, AP0[2], AP0[1]);
        const float M02 = AP0[2];
        const float M10 = fmaf(w0, AP1[2], AP1[0]);
        const float M11 = fmaf(w1, AP1[2], AP1[1]);
        const float M12 = AP1[2];
        const float M20 = fmaf(w0, Pm[8], Pm[6]);
        const float M21 = fmaf(w1, Pm[8], Pm[7]);
        const float M22 = Pm[8];

        const float q01 = expf(2.0f * t2);

        const float S00 = M00 + q01 + 1e-6f;
        const float S11 = M11 + q01 + 1e-6f;
        const float S22 = M22 + EXP_M8_F + 1e-6f;
        const float S01 = 0.5f * (M01 + M10);
        const float S02 = 0.5f * (M02 + M20);
        const float S12 = 0.5f * (M12 + M21);

        ox[3*j + 0] = px_;
        ox[3*j + 1] = py_;
        ox[3*j + 2] = ang_;
        float* o = oP + 9*j;
        o[0] = S00; o[1] = S01; o[2] = S02;
        o[3] = S01; o[4] = S11; o[5] = S12;
        o[6] = S02; o[7] = S12; o[8] = S22;
    }

    // ---- 12 independent float4 stores ----
    float4* gox = (float4*)out_x + t * 3;
    float4* goP = (float4*)out_P + t * 9;
    #pragma unroll
    for (int i = 0; i < 9; ++i) goP[i] = oP4_[i];
    #pragma unroll
    for (int i = 0; i < 3; ++i) gox[i] = ox4[i];
}

extern "C" void kernel_launch(void* const* d_in, const int* in_sizes, int n_in,
                              void* d_out, int out_size, void* d_ws, size_t ws_size,
                              hipStream_t stream) {
    const float* x  = (const float*)d_in[0];   // (B,3)
    const float* P  = (const float*)d_in[1];   // (B,3,3)
    const float* a  = (const float*)d_in[2];   // (B,2)
    const float* th = (const float*)d_in[3];   // (B,3)

    const long long B = (long long)in_sizes[0] / 3;   // 2097152
    float* out_x = (float*)d_out;               // (B,3) first in tuple
    float* out_P = (float*)d_out + B * 3;       // (B,3,3) second

    const int nthreads = (int)(B / 4);          // 4 elements per thread
    const int nblk = (nthreads + 255) / 256;    // 2048 blocks
    belief_step_kernel<<<nblk, 256, 0, stream>>>(x, P, a, th, out_x, out_P);
}

// Round 4
// 226.989 us; speedup vs baseline: 1.0024x; 1.0024x over previous
//
#include <hip/hip_runtime.h>
#include <math.h>

#define DT_F      0.1f
#define PI_F      3.14159265358979323846f
#define TWO_PI_F  6.28318530717958647692f
// exp(-8.0) precomputed
#define EXP_M8_F  0.00033546262790251185f

// One "group" = 4 consecutive elements, so every array slice is whole float4s:
//   P: 9 float4, x: 3, th: 3, a: 2  -> 17 independent loads per group.
struct GroupIn {
    float4 p[9];
    float4 x[3];
    float4 t[3];
    float4 a[2];
};

__device__ __forceinline__ void load_group(GroupIn& r,
                                           const float4* __restrict__ P4,
                                           const float4* __restrict__ x4,
                                           const float4* __restrict__ t4,
                                           const float4* __restrict__ a4,
                                           long long g)
{
    const float4* p  = P4 + g * 9;
    const float4* xx = x4 + g * 3;
    const float4* tt = t4 + g * 3;
    const float4* aa = a4 + g * 2;
    #pragma unroll
    for (int i = 0; i < 9; ++i) r.p[i] = p[i];
    #pragma unroll
    for (int i = 0; i < 3; ++i) r.x[i] = xx[i];
    #pragma unroll
    for (int i = 0; i < 3; ++i) r.t[i] = tt[i];
    #pragma unroll
    for (int i = 0; i < 2; ++i) r.a[i] = aa[i];
}

__device__ __forceinline__ void compute_store(const GroupIn& in,
                                              float4* __restrict__ ox4,
                                              float4* __restrict__ oP4,
                                              long long g)
{
    const float* xv = (const float*)in.x;
    const float* pv = (const float*)in.p;
    const float* av = (const float*)in.a;
    const float* tv = (const float*)in.t;

    float4 rx[3], rP[9];
    float* ox = (float*)rx;
    float* oP = (float*)rP;

    #pragma unroll
    for (int j = 0; j < 4; ++j) {
        const float px  = xv[3*j + 0];
        const float py  = xv[3*j + 1];
        const float ang = xv[3*j + 2];
        const float a0  = av[2*j + 0];
        const float a1  = av[2*j + 1];
        const float t0  = tv[3*j + 0];
        const float t1  = tv[3*j + 1];
        const float t2  = tv[3*j + 2];
        const float* Pm = pv + 9*j;

        // range_angle(ang - theta1*a1*DT)
        const float ar   = ang - t1 * a1 * DT_F;
        const float ang_ = ar - TWO_PI_F * floorf((ar + PI_F) / TWO_PI_F);
        float s, c;
        sincosf(ang_, &s, &c);
        const float v = t0 * a0 * DT_F;

        const float px_ = fminf(fmaxf(px + v * c, -1.0f), 1.0f);
        const float py_ = fminf(fmaxf(py + v * s, -1.0f), 1.0f);

        // A = I with w0 at (0,2), w1 at (1,2); w0 = -v*s, w1 = v*c
        const float w0 = -v * s;
        const float w1 =  v * c;

        float AP0[3], AP1[3];
        #pragma unroll
        for (int k = 0; k < 3; ++k) {
            AP0[k] = fmaf(w0, Pm[6 + k], Pm[0 + k]);
            AP1[k] = fmaf(w1, Pm[6 + k], Pm[3 + k]);
        }

        const float M00 = fmaf(w0, AP0[2], AP0[0]);
        const float M01 = fmaf(w1, AP0[2], AP0[1]);
        const float M02 = AP0[2];
        const float M10 = fmaf(w0, AP1[2], AP1[0]);
        const float M11 = fmaf(w1, AP1[2], AP1[1]);
        const float M12 = AP1[2];
        const float M20 = fmaf(w0, Pm[8], Pm[6]);
        const float M21 = fmaf(w1, Pm[8], Pm[7]);
        const float M22 = Pm[8];

        const float q01 = expf(2.0f * t2);

        const float S00 = M00 + q01 + 1e-6f;
        const float S11 = M11 + q01 + 1e-6f;
        const float S22 = M22 + EXP_M8_F + 1e-6f;
        const float S01 = 0.5f * (M01 + M10);
        const float S02 = 0.5f * (M02 + M20);
        const float S12 = 0.5f * (M12 + M21);

        ox[3*j + 0] = px_;
        ox[3*j + 1] = py_;
        ox[3*j + 2] = ang_;
        float* o = oP + 9*j;
        o[0] = S00; o[1] = S01; o[2] = S02;
        o[3] = S01; o[4] = S11; o[5] = S12;
        o[6] = S02; o[7] = S12; o[8] = S22;
    }

    float4* gx = ox4 + g * 3;
    float4* gP = oP4 + g * 9;
    #pragma unroll
    for (int i = 0; i < 9; ++i) gP[i] = rP[i];
    #pragma unroll
    for (int i = 0; i < 3; ++i) gx[i] = rx[i];
}

// Grid-stride over groups with an explicit 2-deep register double-buffer:
// loads for group n+1 are posted before group n is computed, so each wave
// keeps ~17 float4 loads in flight ~75% of its lifetime.
__global__ __launch_bounds__(256) void belief_step_kernel(
    const float* __restrict__ x,
    const float* __restrict__ P,
    const float* __restrict__ a,
    const float* __restrict__ th,
    float* __restrict__ out_x,
    float* __restrict__ out_P,
    long long G)            // number of 4-element groups
{
    const long long T = (long long)gridDim.x * 256;       // total threads
    long long g = (long long)blockIdx.x * 256 + threadIdx.x;

    const float4* P4 = (const float4*)P;
    const float4* x4 = (const float4*)x;
    const float4* t4 = (const float4*)th;
    const float4* a4 = (const float4*)a;
    float4* ox4 = (float4*)out_x;
    float4* oP4 = (float4*)out_P;

    if (g >= G) return;

    GroupIn A, B;
    long long gA = g;
    load_group(A, P4, x4, t4, a4, gA);
    g += T;

    while (true) {
        // Post next group's loads BEFORE consuming the current one.
        long long gB = -1;
        if (g < G) { gB = g; load_group(B, P4, x4, t4, a4, gB); g += T; }

        compute_store(A, ox4, oP4, gA);
        if (gB < 0) break;

        long long gN = -1;
        if (g < G) { gN = g; load_group(A, P4, x4, t4, a4, gN); g += T; }

        compute_store(B, ox4, oP4, gB);
        if (gN < 0) break;
        gA = gN;
    }
}

extern "C" void kernel_launch(void* const* d_in, const int* in_sizes, int n_in,
                              void* d_out, int out_size, void* d_ws, size_t ws_size,
                              hipStream_t stream) {
    const float* x  = (const float*)d_in[0];   // (B,3)
    const float* P  = (const float*)d_in[1];   // (B,3,3)
    const float* a  = (const float*)d_in[2];   // (B,2)
    const float* th = (const float*)d_in[3];   // (B,3)

    const long long B = (long long)in_sizes[0] / 3;   // 2097152
    float* out_x = (float*)d_out;               // (B,3) first in tuple
    float* out_P = (float*)d_out + B * 3;       // (B,3,3) second

    const long long G = B / 4;                  // 4-element groups
    const int nblk = 512;                       // 2 blocks/CU, 4 groups/thread
    belief_step_kernel<<<nblk, 256, 0, stream>>>(x, P, a, th, out_x, out_P, G);
}

// Round 6
// 215.304 us; speedup vs baseline: 1.0568x; 1.0543x over previous
//
#include <hip/hip_runtime.h>
#include <math.h>

#define DT_F      0.1f
#define PI_F      3.14159265358979323846f
#define TWO_PI_F  6.28318530717958647692f
#define EXP_M8_F  0.00033546262790251185f   // exp(-8.0)

#define TILE            256
#define TILES_PER_BLOCK 4

// float4-slot layout inside one LDS buffer (1088 slots = 17408 B):
//   P @ 0 (576) | x @ 576 (192) | t @ 768 (192) | a @ 960 (128)
// float-offsets: P@0, x@2304, t@3072, a@3840
// output reuse:  P_ @ 0 (576 slots / 2304 floats) | x_ @ 576 (192 slots)

typedef const __attribute__((address_space(1))) void GVoid;
typedef __attribute__((address_space(3))) void LVoid;

__device__ __forceinline__ void gll16(const float4* g, const float4* l) {
    __builtin_amdgcn_global_load_lds((GVoid*)g, (LVoid*)l, 16, 0, 0);
}

#define SCHED_FENCE() __builtin_amdgcn_sched_barrier(0)
#define RAW_BAR() do { SCHED_FENCE(); __builtin_amdgcn_s_barrier(); SCHED_FENCE(); } while (0)

// Post one tile's 17 KB of coalesced loads direct to LDS.
// Per-wave posted counts: w0:6 w1:5 w2:4 w3:2  (all predicates wave-aligned).
__device__ __forceinline__ void stage_tile(const float4* gP, const float4* gx,
                                           const float4* gt, const float4* ga,
                                           float4* buf, int tid) {
    gll16(gP + tid,        buf + tid);
    gll16(gP + 256 + tid,  buf + 256 + tid);
    if (tid < 64)  gll16(gP + 512 + tid, buf + 512 + tid);
    if (tid < 192) gll16(gx + tid,       buf + 576 + tid);
    if (tid < 192) gll16(gt + tid,       buf + 768 + tid);
    if (tid < 128) gll16(ga + tid,       buf + 960 + tid);
}

__global__ __launch_bounds__(256) void belief_step_kernel(
    const float* __restrict__ x,
    const float* __restrict__ P,
    const float* __restrict__ a,
    const float* __restrict__ th,
    float* __restrict__ out_x,
    float* __restrict__ out_P)
{
    __shared__ float4 lds[2][1088];

    const int tid = threadIdx.x;
    const int wid = tid >> 6;
    const long long tile0 = (long long)blockIdx.x * TILES_PER_BLOCK;

    const float4* gP4 = (const float4*)P;
    const float4* gx4 = (const float4*)x;
    const float4* gt4 = (const float4*)th;
    const float4* ga4 = (const float4*)a;
    float4* goX = (float4*)out_x;
    float4* goP = (float4*)out_P;

    // ---- prologue: stage tile0, full drain once ----
    stage_tile(gP4 + tile0 * 576, gx4 + tile0 * 192,
               gt4 + tile0 * 192, ga4 + tile0 * 128, &lds[0][0], tid);
    asm volatile("s_waitcnt vmcnt(0)" ::: "memory");
    RAW_BAR();

    int cur = 0;
    for (int t = 0; t < TILES_PER_BLOCK; ++t) {
        const long long tile = tile0 + t;
        const bool have_next = (t + 1 < TILES_PER_BLOCK);

        // 1. post next tile's loads into the other buffer (stays in flight
        //    across this entire iteration — never drained to 0).
        if (have_next) {
            const long long nt = tile + 1;
            stage_tile(gP4 + nt * 576, gx4 + nt * 192,
                       gt4 + nt * 192, ga4 + nt * 128, &lds[cur ^ 1][0], tid);
        }

        // 2. per-thread gather from LDS (stride 3/9 = free 2-way alias)
        const float* bf = (const float*)&lds[cur][0];
        const float px  = bf[2304 + tid * 3 + 0];
        const float py  = bf[2304 + tid * 3 + 1];
        const float ang = bf[2304 + tid * 3 + 2];
        const float t0  = bf[3072 + tid * 3 + 0];
        const float t1  = bf[3072 + tid * 3 + 1];
        const float t2  = bf[3072 + tid * 3 + 2];
        const float a0  = bf[3840 + tid * 2 + 0];
        const float a1  = bf[3840 + tid * 2 + 1];
        float Pm[9];
        #pragma unroll
        for (int j = 0; j < 9; ++j) Pm[j] = bf[tid * 9 + j];

        // 3. compute (registers only) — exact reference formulas
        const float ar   = ang - t1 * a1 * DT_F;
        const float ang_ = ar - TWO_PI_F * floorf((ar + PI_F) / TWO_PI_F);
        float s, c;
        sincosf(ang_, &s, &c);
        const float v = t0 * a0 * DT_F;

        const float px_ = fminf(fmaxf(px + v * c, -1.0f), 1.0f);
        const float py_ = fminf(fmaxf(py + v * s, -1.0f), 1.0f);

        const float w0 = -v * s;
        const float w1 =  v * c;

        float AP0[3], AP1[3];
        #pragma unroll
        for (int k = 0; k < 3; ++k) {
            AP0[k] = fmaf(w0, Pm[6 + k], Pm[0 + k]);
            AP1[k] = fmaf(w1, Pm[6 + k], Pm[3 + k]);
        }
        const float M00 = fmaf(w0, AP0[2], AP0[0]);
        const float M01 = fmaf(w1, AP0[2], AP0[1]);
        const float M02 = AP0[2];
        const float M10 = fmaf(w0, AP1[2], AP1[0]);
        const float M11 = fmaf(w1, AP1[2], AP1[1]);
        const float M12 = AP1[2];
        const float M20 = fmaf(w0, Pm[8], Pm[6]);
        const float M21 = fmaf(w1, Pm[8], Pm[7]);
        const float M22 = Pm[8];

        const float q01 = expf(2.0f * t2);
        const float S00 = M00 + q01 + 1e-6f;
        const float S11 = M11 + q01 + 1e-6f;
        const float S22 = M22 + EXP_M8_F + 1e-6f;
        const float S01 = 0.5f * (M01 + M10);
        const float S02 = 0.5f * (M02 + M20);
        const float S12 = 0.5f * (M12 + M21);

        // 4. all waves done reading this buffer
        RAW_BAR();

        // 5. scatter outputs into the just-consumed buffer
        float* bw = (float*)&lds[cur][0];
        bw[tid * 9 + 0] = S00;
        bw[tid * 9 + 1] = S01;
        bw[tid * 9 + 2] = S02;
        bw[tid * 9 + 3] = S01;
        bw[tid * 9 + 4] = S11;
        bw[tid * 9 + 5] = S12;
        bw[tid * 9 + 6] = S02;
        bw[tid * 9 + 7] = S12;
        bw[tid * 9 + 8] = S22;
        bw[2304 + tid * 3 + 0] = px_;
        bw[2304 + tid * 3 + 1] = py_;
        bw[2304 + tid * 3 + 2] = ang_;
        asm volatile("s_waitcnt lgkmcnt(0)" ::: "memory");
        // 6. out-staging visible to all waves
        RAW_BAR();

        // 7. coalesced float4 stores (per-wave store counts: w0:4 w1:3 w2:3 w3:2)
        const float4* b4 = &lds[cur][0];
        {
            float4 r0 = b4[tid];
            float4 r1 = b4[tid + 256];
            goP[tile * 576 + tid]       = r0;
            goP[tile * 576 + 256 + tid] = r1;
            if (tid < 64) {
                float4 r2 = b4[tid + 512];
                goP[tile * 576 + 512 + tid] = r2;
            }
            if (tid < 192) {
                float4 r3 = b4[576 + tid];
                goX[tile * 192 + tid] = r3;
            }
        }

        // 8. counted wait: next tile's DMA complete; only this iter's stores
        //    (issued after the stage) may remain outstanding.
        if (have_next) {
            if (wid == 0)      asm volatile("s_waitcnt vmcnt(4)" ::: "memory");
            else if (wid == 3) asm volatile("s_waitcnt vmcnt(2)" ::: "memory");
            else               asm volatile("s_waitcnt vmcnt(3)" ::: "memory");
            SCHED_FENCE();
        }
        // 9. rendezvous; next iteration may overwrite lds[cur]
        RAW_BAR();
        cur ^= 1;
    }
}

extern "C" void kernel_launch(void* const* d_in, const int* in_sizes, int n_in,
                              void* d_out, int out_size, void* d_ws, size_t ws_size,
                              hipStream_t stream) {
    const float* x  = (const float*)d_in[0];   // (B,3)
    const float* P  = (const float*)d_in[1];   // (B,3,3)
    const float* a  = (const float*)d_in[2];   // (B,2)
    const float* th = (const float*)d_in[3];   // (B,3)

    const long long B = (long long)in_sizes[0] / 3;   // 2097152
    float* out_x = (float*)d_out;               // (B,3) first in tuple
    float* out_P = (float*)d_out + B * 3;       // (B,3,3) second

    const long long ntiles = B / TILE;                      // 8192
    const int nblk = (int)(ntiles / TILES_PER_BLOCK);       // 2048
    belief_step_kernel<<<nblk, 256, 0, stream>>>(x, P, a, th, out_x, out_P);
}

// Round 7
// 214.963 us; speedup vs baseline: 1.0585x; 1.0016x over previous
//
#include <hip/hip_runtime.h>
#include <math.h>

#define DT_F          0.1f
#define PI_F          3.14159265358979323846f
#define TWO_PI_F      6.28318530717958647692f
#define INV_TWO_PI_F  0.15915494309189535f
#define EXP_M8_F      0.00033546262790251185f   // exp(-8.0)

#define TPW 4     // tiles per wave; tile = 64 elements (one per lane)

// Per-wave LDS region: 320 float4 slots (5120 B).
//   float4 slots: P [0,144) | x [144,192) | t [192,240) | a [240,272) | pad [272,320)
//   float offsets: P@0..575 | x@576..767 | t@768..959 | a@960..1087 | pad@1088..
// Outputs written IN PLACE: P_ over P (own element), x_ over x (own element).

typedef const __attribute__((address_space(1))) void GVoid;
typedef __attribute__((address_space(3))) void LVoid;

// global_load_lds: LDS dest = first-active-lane base + lane*16 (lane-linear);
// global source is PER-LANE (m173 pattern).
__device__ __forceinline__ void gll16(const float4* g, float4* l) {
    __builtin_amdgcn_global_load_lds((GVoid*)g, (LVoid*)l, 16, 0, 0);
}
#define SCHED_FENCE() __builtin_amdgcn_sched_barrier(0)

__global__ __launch_bounds__(256) void belief_step_kernel(
    const float* __restrict__ x,
    const float* __restrict__ P,
    const float* __restrict__ a,
    const float* __restrict__ th,
    float* __restrict__ out_x,
    float* __restrict__ out_P)
{
    __shared__ float4 lds[4][320];   // 20480 B -> 8 blocks/CU, whole grid resident

    const int tid  = threadIdx.x;
    const int lane = tid & 63;
    const int wid  = tid >> 6;
    float4* buf = &lds[wid][0];
    float*  bf  = (float*)buf;

    const long long wave = (long long)blockIdx.x * 4 + wid;

    const float4* P4g = (const float4*)P;
    const float4* x4g = (const float4*)x;
    const float4* t4g = (const float4*)th;
    const float4* a4g = (const float4*)a;
    float4* oP4 = (float4*)out_P;
    float4* oX4 = (float4*)out_x;

    for (int k = 0; k < TPW; ++k) {
        const long long tile = wave * TPW + k;   // 64-element tile index
        const float4* Pt = P4g + tile * 144;
        const float4* xt = x4g + tile * 48;
        const float4* tt = t4g + tile * 48;
        const float4* at = a4g + tile * 32;

        // ---- 5 full-wave DMA posts, LDS lane-linear, per-lane global src ----
        gll16(Pt + lane,        buf + lane);            // slots   0..63  (P)
        gll16(Pt + 64 + lane,   buf + 64 + lane);       // slots  64..127 (P)
        {   // slots 128..191: lanes 0..15 -> P[128..143], lanes 16..63 -> x[0..47]
            const float4* g = (lane < 16) ? (Pt + 128 + lane) : (xt + (lane - 16));
            gll16(g, buf + 128 + lane);
        }
        {   // slots 192..255: lanes 0..47 -> t[0..47], lanes 48..63 -> a[0..15]
            const float4* g = (lane < 48) ? (tt + lane) : (at + (lane - 48));
            gll16(g, buf + 192 + lane);
        }
        {   // slots 256..319: lanes 0..15 -> a[16..31]; rest pad (clamped re-read)
            const int ai = (16 + lane < 32) ? (16 + lane) : 31;
            gll16(at + ai, buf + 256 + lane);
        }
        asm volatile("s_waitcnt vmcnt(0)" ::: "memory");  // this wave's DMA done
        SCHED_FENCE();

        // ---- per-lane gather (element = lane; strides 9/3/2 = free 2-way) ----
        float Pm[9];
        #pragma unroll
        for (int j = 0; j < 9; ++j) Pm[j] = bf[9 * lane + j];
        const float px  = bf[576 + 3 * lane + 0];
        const float py  = bf[576 + 3 * lane + 1];
        const float ang = bf[576 + 3 * lane + 2];
        const float t0  = bf[768 + 3 * lane + 0];
        const float t1  = bf[768 + 3 * lane + 1];
        const float t2  = bf[768 + 3 * lane + 2];
        const float a0  = bf[960 + 2 * lane + 0];
        const float a1  = bf[960 + 2 * lane + 1];

        // ---- compute (fast HW trig; exact reference formulas otherwise) ----
        const float ar   = ang - t1 * a1 * DT_F;
        const float ang_ = ar - TWO_PI_F * floorf((ar + PI_F) * INV_TWO_PI_F);
        const float s = __sinf(ang_);            // v_sin_f32 (revolution-scaled)
        const float c = __cosf(ang_);
        const float v = t0 * a0 * DT_F;

        const float px_ = fminf(fmaxf(px + v * c, -1.0f), 1.0f);
        const float py_ = fminf(fmaxf(py + v * s, -1.0f), 1.0f);

        const float w0 = -v * s;
        const float w1 =  v * c;

        float AP0[3], AP1[3];
        #pragma unroll
        for (int m = 0; m < 3; ++m) {
            AP0[m] = fmaf(w0, Pm[6 + m], Pm[0 + m]);
            AP1[m] = fmaf(w1, Pm[6 + m], Pm[3 + m]);
        }
        const float M00 = fmaf(w0, AP0[2], AP0[0]);
        const float M01 = fmaf(w1, AP0[2], AP0[1]);
        const float M02 = AP0[2];
        const float M10 = fmaf(w0, AP1[2], AP1[0]);
        const float M11 = fmaf(w1, AP1[2], AP1[1]);
        const float M12 = AP1[2];
        const float M20 = fmaf(w0, Pm[8], Pm[6]);
        const float M21 = fmaf(w1, Pm[8], Pm[7]);
        const float M22 = Pm[8];

        const float q01 = __expf(2.0f * t2);     // v_exp_f32 path
        const float S00 = M00 + q01 + 1e-6f;
        const float S11 = M11 + q01 + 1e-6f;
        const float S22 = M22 + EXP_M8_F + 1e-6f;
        const float S01 = 0.5f * (M01 + M10);
        const float S02 = 0.5f * (M02 + M20);
        const float S12 = 0.5f * (M12 + M21);

        // ---- in-place scatter: own element's slots only (race-free, no bar) ----
        bf[9 * lane + 0] = S00;
        bf[9 * lane + 1] = S01;
        bf[9 * lane + 2] = S02;
        bf[9 * lane + 3] = S01;
        bf[9 * lane + 4] = S11;
        bf[9 * lane + 5] = S12;
        bf[9 * lane + 6] = S02;
        bf[9 * lane + 7] = S12;
        bf[9 * lane + 8] = S22;
        bf[576 + 3 * lane + 0] = px_;
        bf[576 + 3 * lane + 1] = py_;
        bf[576 + 3 * lane + 2] = ang_;

        // ---- coalesced readback + per-lane-addressed stores ----
        // (compiler orders ds_write -> ds_read via lgkmcnt; stores depend on reads,
        //  so next iteration's DMA cannot land before these reads complete)
        const float4 r0 = buf[lane];             // P_ slots 0..63
        const float4 r1 = buf[64 + lane];        // P_ slots 64..127
        const float4 r2 = buf[128 + lane];       // lanes<16: P_ tail, else x_
        float4* dP = oP4 + tile * 144;
        float4* dX = oX4 + tile * 48;
        dP[lane]      = r0;
        dP[64 + lane] = r1;
        float4* d2 = (lane < 16) ? (dP + 128 + lane) : (dX + (lane - 16));
        *d2 = r2;
    }
}

extern "C" void kernel_launch(void* const* d_in, const int* in_sizes, int n_in,
                              void* d_out, int out_size, void* d_ws, size_t ws_size,
                              hipStream_t stream) {
    const float* x  = (const float*)d_in[0];   // (B,3)
    const float* P  = (const float*)d_in[1];   // (B,3,3)
    const float* a  = (const float*)d_in[2];   // (B,2)
    const float* th = (const float*)d_in[3];   // (B,3)

    const long long B = (long long)in_sizes[0] / 3;   // 2097152
    float* out_x = (float*)d_out;               // (B,3) first in tuple
    float* out_P = (float*)d_out + B * 3;       // (B,3,3) second

    // 64-elem tiles: 32768 total; 4 per wave -> 8192 waves -> 2048 blocks.
    // 20480 B LDS/block -> 8 blocks/CU -> entire grid co-resident.
    const long long ntiles = B / 64;
    const int nwaves = (int)(ntiles / TPW);
    const int nblk   = nwaves / 4;
    belief_step_kernel<<<nblk, 256, 0, stream>>>(x, P, a, th, out_x, out_P);
}